// Round 8
// baseline (219.946 us; speedup 1.0000x reference)
//
#include <hip/hip_runtime.h>
#include <cmath>

#define B_   128
#define H_   256
#define W_   256
#define WC_  129
#define L_   182
#define PI_F 3.14159265358979f

// Dynamic-LDS layout for the fused kernel:
//   cols4[128][65]  float4  (A.re,A.im,B.re,B.im) per (row-pair, k_local)  = 133120 B
//   lbins[182], lcnt[182]                                                  = 1456 B
#define COLS_ELEMS (128 * 65)
#define SMEM_BYTES (COLS_ELEMS * 16 + 2 * L_ * 4)

// ---------------------------------------------------------------------------
// Cross-lane DIF stage for 4 FFTs in the s = 4l+j layout, shared twiddles.
// Sub-FFT size N' = 8h; CT/ST = cos/sin(pi/(4h)).  (verified R7, absmax 0)
// ---------------------------------------------------------------------------
__device__ __forceinline__ void stage4(float (&vr)[4][4], float (&vi)[4][4],
                                       int l, int h, float CT, float ST) {
  int i = l & (h - 1);
  float s, c;
  __sincosf(-PI_F * (float)i / (float)h, &s, &c);
  float wr[4], wi[4];
  wr[0] = c;                       wi[0] = s;
  wr[1] = c * CT + s * ST;         wi[1] = s * CT - c * ST;
  wr[2] = wr[1] * CT + wi[1] * ST; wi[2] = wi[1] * CT - wr[1] * ST;
  wr[3] = wr[2] * CT + wi[2] * ST; wi[3] = wi[2] * CT - wr[2] * ST;
  bool up = (l & h) != 0;
  float sgn = up ? -1.f : 1.f;
  #pragma unroll
  for (int f = 0; f < 4; ++f) {
    #pragma unroll
    for (int j = 0; j < 4; ++j) {
      float br = __shfl_xor(vr[f][j], h, 64);
      float bi = __shfl_xor(vi[f][j], h, 64);
      float tr = fmaf(sgn, vr[f][j], br);
      float ti = fmaf(sgn, vi[f][j], bi);
      float cc = up ? wr[j] : 1.f;
      float ss = up ? wi[j] : 0.f;
      vr[f][j] = tr * cc - ti * ss;
      vi[f][j] = tr * ss + ti * cc;
    }
  }
}

// Full 256-pt DIF FFT x4 (s = 4l+j layout): 6 cross-lane stages + in-lane
// radix-4 tail. Output: storage s = 4l+j holds X[bitrev8(s)],
// i.e. frequency f = 64*br2(j) + br6(l).
__device__ __forceinline__ void fft256x4(float (&vr)[4][4], float (&vi)[4][4],
                                         int l) {
  stage4(vr, vi, l, 32, 0.9996988187f, 0.0245412285f);  // N'=256
  stage4(vr, vi, l, 16, 0.9987954562f, 0.0490676743f);  // N'=128
  stage4(vr, vi, l,  8, 0.9951847267f, 0.0980171403f);  // N'=64
  stage4(vr, vi, l,  4, 0.9807852804f, 0.1950903220f);  // N'=32
  stage4(vr, vi, l,  2, 0.9238795325f, 0.3826834324f);  // N'=16
  stage4(vr, vi, l,  1, 0.7071067812f, 0.7071067812f);  // N'=8
  #pragma unroll
  for (int f = 0; f < 4; ++f) {
    float u0r = vr[f][0] + vr[f][2], u0i = vi[f][0] + vi[f][2];
    float v0r = vr[f][0] - vr[f][2], v0i = vi[f][0] - vi[f][2];
    float u1r = vr[f][1] + vr[f][3], u1i = vi[f][1] + vi[f][3];
    float d1r = vr[f][1] - vr[f][3], d1i = vi[f][1] - vi[f][3];
    float v1r = d1i, v1i = -d1r;                 // (x1-x3)*(-i)
    vr[f][0] = u0r + u1r; vi[f][0] = u0i + u1i;
    vr[f][1] = u0r - u1r; vi[f][1] = u0i - u1i;
    vr[f][2] = v0r + v1r; vi[f][2] = v0i + v1i;
    vr[f][3] = v0r - v1r; vi[f][3] = v0i - v1i;
  }
}

__device__ __forceinline__ float4 luma4(float4 r, float4 g, float4 b) {
  float4 o;
  o.x = fmaf(0.299f, r.x, fmaf(0.587f, g.x, 0.114f * b.x));
  o.y = fmaf(0.299f, r.y, fmaf(0.587f, g.y, 0.114f * b.y));
  o.z = fmaf(0.299f, r.z, fmaf(0.587f, g.z, 0.114f * b.z));
  o.w = fmaf(0.299f, r.w, fmaf(0.587f, g.w, 0.114f * b.w));
  return o;
}

// ---------------------------------------------------------------------------
// Fused spectral kernel. Block = (image b, k-half). 1024 thr = 16 waves.
// Phase 1: all 128 row-pair real FFTs (redundant across the 2 halves; compute
//   is cheap), conjugate-symmetry unpack in-wave (partner of storage slot
//   (l,j) is slot 3-j of lane br6(64-br6(l)); lane 0 self-contained), keep
//   only this block's k-range in LDS.
// Phase 2: column FFTs from LDS, log-power, radial binning, 182 partials out.
// ---------------------------------------------------------------------------
__global__ __launch_bounds__(1024) void fused_kernel(
    const float* __restrict__ data, const int* __restrict__ radius,
    float* __restrict__ partial, float* __restrict__ cntpart) {
  extern __shared__ char smem[];
  float4* cols4 = (float4*)smem;
  float* lbins = (float*)(smem + COLS_ELEMS * 16);
  float* lcnt  = lbins + L_;

  int tid = threadIdx.x;
  int w = tid >> 6, l = tid & 63;
  int bid = blockIdx.x;
  int b = bid >> 1;
  int half = bid & 1;
  int k0h = half ? 65 : 0;
  int klcount = half ? 64 : 65;
  bool do_cnt = (bid < 2);

  for (int i = tid; i < L_; i += 1024) { lbins[i] = 0.f; lcnt[i] = 0.f; }

  const float* img = data + ((size_t)b * 3) * (H_ * W_);
  const int m = (int)(__brev((unsigned)l) >> 26);         // br6(l)
  const int m2 = (64 - m) & 63;
  const int l2 = (int)(__brev((unsigned)m2) >> 26);       // partner lane
  const int amap[4] = {0, 2, 1, 3};                       // br2(j)

  // ---- Phase 1: row-pair FFTs (wave w covers row-pairs 8w..8w+7) ----
  #pragma unroll
  for (int bt = 0; bt < 2; ++bt) {
    float vr[4][4], vi[4][4];
    #pragma unroll
    for (int hb = 0; hb < 2; ++hb) {
      float4 ra[2], ga[2], ba[2], rb[2], gb[2], bb[2];
      #pragma unroll
      for (int e = 0; e < 2; ++e) {
        int f = hb * 2 + e;
        int p = w * 8 + bt * 4 + f;
        const float* pA = img + (size_t)(2 * p) * W_ + 4 * l;
        ra[e] = *(const float4*)(pA);
        ga[e] = *(const float4*)(pA + H_ * W_);
        ba[e] = *(const float4*)(pA + 2 * H_ * W_);
        rb[e] = *(const float4*)(pA + W_);
        gb[e] = *(const float4*)(pA + H_ * W_ + W_);
        bb[e] = *(const float4*)(pA + 2 * H_ * W_ + W_);
      }
      #pragma unroll
      for (int e = 0; e < 2; ++e) {
        int f = hb * 2 + e;
        float4 A = luma4(ra[e], ga[e], ba[e]);
        float4 Bv = luma4(rb[e], gb[e], bb[e]);
        vr[f][0] = A.x; vr[f][1] = A.y; vr[f][2] = A.z; vr[f][3] = A.w;
        vi[f][0] = Bv.x; vi[f][1] = Bv.y; vi[f][2] = Bv.z; vi[f][3] = Bv.w;
      }
    }
    fft256x4(vr, vi, l);
    // unpack A/B via conjugate symmetry; store this half's k-range
    #pragma unroll
    for (int f = 0; f < 4; ++f) {
      int p = w * 8 + bt * 4 + f;
      #pragma unroll
      for (int j = 0; j < 3; ++j) {   // j=3 -> k in [192,255], never kept
        int k = (amap[j] << 6) | m;
        float pr = __shfl(vr[f][3 - j], l2, 64);
        float pi = __shfl(vi[f][3 - j], l2, 64);
        if (l == 0) {                 // lane 0: partner in own registers
          int js = (j < 2) ? j : (5 - j);   // {0,1,3}
          pr = vr[f][js]; pi = vi[f][js];
        }
        int kl = k - k0h;
        if (kl >= 0 && kl < klcount) {
          float4 o;
          o.x = 0.5f * (vr[f][j] + pr);   // A.re
          o.y = 0.5f * (vi[f][j] - pi);   // A.im
          o.z = 0.5f * (vi[f][j] + pi);   // B.re
          o.w = 0.5f * (pr - vr[f][j]);   // B.im
          cols4[p * 65 + kl] = o;
        }
      }
    }
  }
  __syncthreads();

  // ---- Phase 2: column FFTs + binning ----
  int tmax = (klcount + 3) >> 2;   // 17 (half0) or 16 (half1)
  for (int t = w; t < tmax; t += 16) {
    float vr[4][4], vi[4][4];
    #pragma unroll
    for (int ff = 0; ff < 4; ++ff) {
      int kl = 4 * t + ff;
      int klr = (kl < klcount) ? kl : 0;
      float4 c0 = cols4[(2 * l) * 65 + klr];
      float4 c1 = cols4[(2 * l + 1) * 65 + klr];
      vr[ff][0] = c0.x; vi[ff][0] = c0.y;   // row 4l
      vr[ff][1] = c0.z; vi[ff][1] = c0.w;   // row 4l+1
      vr[ff][2] = c1.x; vi[ff][2] = c1.y;   // row 4l+2
      vr[ff][3] = c1.z; vi[ff][3] = c1.w;   // row 4l+3
    }
    fft256x4(vr, vi, l);
    #pragma unroll
    for (int ff = 0; ff < 4; ++ff) {
      int kl = 4 * t + ff;
      if (kl < klcount) {
        int kabs = k0h + kl;
        #pragma unroll
        for (int j = 0; j < 4; ++j) {
          int frow = (amap[j] << 6) | m;
          int bin = radius[frow * WC_ + kabs];
          float pw = vr[ff][j] * vr[ff][j] + vi[ff][j] * vi[ff][j];
          float val = 20.f * __logf(pw + 1e-8f);
          atomicAdd(&lbins[bin], val);
          if (do_cnt) atomicAdd(&lcnt[bin], 1.f);
        }
      }
    }
  }
  __syncthreads();
  float* pp = partial + (size_t)bid * L_;
  for (int i = tid; i < L_; i += 1024) pp[i] = lbins[i];
  if (do_cnt) {
    float* cp = cntpart + (size_t)half * L_;
    for (int i = tid; i < L_; i += 1024) cp[i] = lcnt[i];
  }
}

// One block per batch sample: reduce the 2 half partials, segment mean,
// min-max normalize, L1 vs mean. Plain store of per-sample loss.
__global__ __launch_bounds__(256) void loss_kernel(
    const float* __restrict__ partial, const float* __restrict__ cntpart,
    const float* __restrict__ mean, float* __restrict__ lpart) {
  int b = blockIdx.x;
  int t = threadIdx.x;
  __shared__ float prof[L_];
  __shared__ float red[256];
  if (t < L_) {
    float acc  = partial[(size_t)(b * 2) * L_ + t] +
                 partial[(size_t)(b * 2 + 1) * L_ + t];
    float csum = cntpart[t] + cntpart[L_ + t];
    prof[t] = acc / csum;
  }
  __syncthreads();
  red[t] = (t < L_) ? prof[t] : INFINITY;
  __syncthreads();
  for (int s = 128; s > 0; s >>= 1) {
    if (t < s) red[t] = fminf(red[t], red[t + s]);
    __syncthreads();
  }
  float mn = red[0];
  __syncthreads();
  red[t] = (t < L_) ? (prof[t] - mn) : -INFINITY;
  __syncthreads();
  for (int s = 128; s > 0; s >>= 1) {
    if (t < s) red[t] = fmaxf(red[t], red[t + s]);
    __syncthreads();
  }
  float mx = red[0];
  __syncthreads();
  red[t] = (t < L_) ? fabsf((prof[t] - mn) / mx - mean[t]) : 0.f;
  __syncthreads();
  for (int s = 128; s > 0; s >>= 1) {
    if (t < s) red[t] += red[t + s];
    __syncthreads();
  }
  if (t == 0) lpart[b] = red[0];
}

// Final: one wave sums the 128 per-sample losses, plain store to out.
__global__ __launch_bounds__(64) void final_kernel(
    const float* __restrict__ lpart, float* __restrict__ out) {
  int l = threadIdx.x;
  float v = lpart[l] + lpart[l + 64];
  #pragma unroll
  for (int h = 32; h >= 1; h >>= 1) v += __shfl_xor(v, h, 64);
  if (l == 0) out[0] = v;
}

extern "C" void kernel_launch(void* const* d_in, const int* in_sizes, int n_in,
                              void* d_out, int out_size, void* d_ws, size_t ws_size,
                              hipStream_t stream) {
  const float* data   = (const float*)d_in[0];  // [128,3,256,256] f32
  const float* mean   = (const float*)d_in[1];  // [182] f32
  const int*   radius = (const int*)d_in[2];    // [256,129] i32
  float* out = (float*)d_out;                   // scalar f32

  float* partial = (float*)d_ws;                // [256][L]
  float* cntpart = partial + (size_t)256 * L_;  // [2][L]
  float* lpart   = cntpart + 2 * L_;            // [B]

  // allow >64 KB dynamic LDS (host-side attribute, graph-capture safe)
  (void)hipFuncSetAttribute((const void*)fused_kernel,
                            hipFuncAttributeMaxDynamicSharedMemorySize,
                            SMEM_BYTES);

  fused_kernel<<<B_ * 2, 1024, SMEM_BYTES, stream>>>(data, radius, partial, cntpart);
  loss_kernel<<<B_, 256, 0, stream>>>(partial, cntpart, mean, lpart);
  final_kernel<<<1, 64, 0, stream>>>(lpart, out);
}